// Round 13
// baseline (208.624 us; speedup 1.0000x reference)
//
#include <hip/hip_runtime.h>

// CapsuleLayer dynamic routing — two-phase, fp32-exact.
//   P[k,b,r,o] = sum_c x[b,r,c] * w[k,r,c,o]   (K=B=32, R=2048, C=16, O=32)
//   u0 = sigmoid(colsum(P)/R); f(v) = P^T softmax(P v)
//   u1 = sigmoid(f(u0)); out = sigmoid(f(u0+u1))
//
// R10 (178.8 us) = verified floor of the lane structure. R10 null (burst
// depth) + R11 negative (more waves) => priors is L1-MSHR-limited on the
// cold single-use w stream. R12b = exact R10 with nontemporal w loads
// (bypass L1 allocation; w is single-use), via ext_vector_type to satisfy
// the builtin's pointer-type requirement (R12 compile fix). x loads normal
// (L2-warm, reused); P stores normal. Route/transpose/fallback identical.

#define KK 32
#define BB 32
#define RR 2048
#define CC 16
#define OO 32

__device__ __forceinline__ float sigmoidf_(float v) {
  return 1.0f / (1.0f + __expf(-v));
}

typedef float v4f __attribute__((ext_vector_type(4)));

__device__ __forceinline__ float4 ntload4(const float* p) {
  v4f v = __builtin_nontemporal_load((const v4f*)p);
  return make_float4(v.x, v.y, v.z, v.w);
}

// ---------------- Phase 0: x[B][R][C] -> xT[R][C][B] (once) ----------------
__global__ void __launch_bounds__(256)
transpose_x(const float* __restrict__ x, float* __restrict__ xT) {
  const int r = blockIdx.x;          // 0..2047
  const int t = threadIdx.x;
  const int b = t >> 3;              // 0..31
  const int c = (t & 7) * 2;         // 0,2,..,14
  const float2 v = *(const float2*)(x + ((size_t)b * RR + r) * CC + c);
  xT[((size_t)r * CC + c) * BB + b]     = v.x;
  xT[((size_t)r * CC + c + 1) * BB + b] = v.y;
}

// ---------------- Phase 1: priors einsum (R10 + nontemporal w) -------------
// grid = KCHUNK*128 x 256 thr. Block = (kl = bid>>7, 16-row tile rt).
// Lane: og = l&3, bg = (l>>2)&3, rq = l>>4; wave wid owns rows wid*4+rq.
// Thread tile 8b x 8o (acc 64 VGPR). Loads in 2-c pairs; w via nt-load.
// NO min-waves launch_bounds arg (R5/R9 spill trap).
__global__ void __launch_bounds__(256)
capsule_priors3(const float* __restrict__ xT, const float* __restrict__ w,
                float* __restrict__ P, int k0) {
  const int bid  = blockIdx.x;
  const int kl   = bid >> 7;
  const int rt   = bid & 127;
  const int t    = threadIdx.x;
  const int lane = t & 63;
  const int wid  = t >> 6;           // 0..3
  const int og   = lane & 3;
  const int bg   = (lane >> 2) & 3;
  const int rq   = lane >> 4;        // 0..3
  const int r    = rt * 16 + wid * 4 + rq;
  const int k    = k0 + kl;

  const float* __restrict__ xr = xT + ((size_t)r * CC) * BB + bg * 8;
  const float* __restrict__ wr = w + (size_t)k * ((size_t)RR * CC * OO)
                                   + ((size_t)r * CC) * OO + og * 8;

  float4 acc[8][2];
  #pragma unroll
  for (int bb = 0; bb < 8; ++bb) {
    acc[bb][0] = make_float4(0.f, 0.f, 0.f, 0.f);
    acc[bb][1] = make_float4(0.f, 0.f, 0.f, 0.f);
  }

  #pragma unroll
  for (int q = 0; q < 8; ++q) {
    // pair burst: 8 independent loads for c = 2q, 2q+1 (w loads bypass L1)
    float4 xfA0, xfA1, wfA0, wfA1, xfB0, xfB1, wfB0, wfB1;
    {
      const int cA = 2 * q, cB = 2 * q + 1;
      xfA0 = *(const float4*)(xr + cA * BB);
      xfA1 = *(const float4*)(xr + cA * BB + 4);
      wfA0 = ntload4(wr + cA * OO);
      wfA1 = ntload4(wr + cA * OO + 4);
      xfB0 = *(const float4*)(xr + cB * BB);
      xfB1 = *(const float4*)(xr + cB * BB + 4);
      wfB0 = ntload4(wr + cB * OO);
      wfB1 = ntload4(wr + cB * OO + 4);
    }
    {
      const float xs[8] = {xfA0.x, xfA0.y, xfA0.z, xfA0.w,
                           xfA1.x, xfA1.y, xfA1.z, xfA1.w};
      #pragma unroll
      for (int bb = 0; bb < 8; ++bb) {
        const float s = xs[bb];
        acc[bb][0].x = fmaf(s, wfA0.x, acc[bb][0].x);
        acc[bb][0].y = fmaf(s, wfA0.y, acc[bb][0].y);
        acc[bb][0].z = fmaf(s, wfA0.z, acc[bb][0].z);
        acc[bb][0].w = fmaf(s, wfA0.w, acc[bb][0].w);
        acc[bb][1].x = fmaf(s, wfA1.x, acc[bb][1].x);
        acc[bb][1].y = fmaf(s, wfA1.y, acc[bb][1].y);
        acc[bb][1].z = fmaf(s, wfA1.z, acc[bb][1].z);
        acc[bb][1].w = fmaf(s, wfA1.w, acc[bb][1].w);
      }
    }
    {
      const float xs[8] = {xfB0.x, xfB0.y, xfB0.z, xfB0.w,
                           xfB1.x, xfB1.y, xfB1.z, xfB1.w};
      #pragma unroll
      for (int bb = 0; bb < 8; ++bb) {
        const float s = xs[bb];
        acc[bb][0].x = fmaf(s, wfB0.x, acc[bb][0].x);
        acc[bb][0].y = fmaf(s, wfB0.y, acc[bb][0].y);
        acc[bb][0].z = fmaf(s, wfB0.z, acc[bb][0].z);
        acc[bb][0].w = fmaf(s, wfB0.w, acc[bb][0].w);
        acc[bb][1].x = fmaf(s, wfB1.x, acc[bb][1].x);
        acc[bb][1].y = fmaf(s, wfB1.y, acc[bb][1].y);
        acc[bb][1].z = fmaf(s, wfB1.z, acc[bb][1].z);
        acc[bb][1].w = fmaf(s, wfB1.w, acc[bb][1].w);
      }
    }
  }

  #pragma unroll
  for (int bb = 0; bb < 8; ++bb) {
    const int b = bg * 8 + bb;
    float* Pd = P + (((size_t)kl * BB + b) * RR + r) * OO + og * 8;
    *(float4*)(Pd)     = acc[bb][0];
    *(float4*)(Pd + 4) = acc[bb][1];
  }
}

// ---------------- Phase 2: routing (unchanged from R3/R4/R6, verified) ----
__global__ void __launch_bounds__(1024, 4)
capsule_route(const float* __restrict__ P, float* __restrict__ out, int k0) {
  __shared__ float swv[512];
  __shared__ float sU[32];
  __shared__ float sM[16];
  __shared__ float sZ[16];

  const int bid  = blockIdx.x;
  const int kl   = bid >> 5;
  const int b    = bid & 31;
  const int t    = threadIdx.x;
  const int o4   = t & 7;
  const int G    = t >> 3;
  const int lane = t & 63;
  const int wid  = t >> 6;

  const float* __restrict__ Pb = P + ((size_t)kl * BB + b) * ((size_t)RR * OO);

  float4 preg[16];
  float4 cs = make_float4(0.f, 0.f, 0.f, 0.f);
  #pragma unroll
  for (int j = 0; j < 16; ++j) {
    preg[j] = *(const float4*)(Pb + (size_t)(j * 128 + G) * OO + (o4 << 2));
    cs.x += preg[j].x; cs.y += preg[j].y; cs.z += preg[j].z; cs.w += preg[j].w;
  }

  #pragma unroll
  for (int m = 8; m <= 32; m <<= 1) {
    cs.x += __shfl_xor(cs.x, m);
    cs.y += __shfl_xor(cs.y, m);
    cs.z += __shfl_xor(cs.z, m);
    cs.w += __shfl_xor(cs.w, m);
  }
  if (lane < 8) *(float4*)&swv[(wid << 5) + (o4 << 2)] = cs;
  __syncthreads();
  if (t < OO) {
    float s = 0.f;
    #pragma unroll
    for (int w2 = 0; w2 < 16; ++w2) s += swv[(w2 << 5) + t];
    sU[t] = sigmoidf_(s * (1.0f / 2048.0f));
  }
  __syncthreads();

  #pragma unroll 1
  for (int pass = 0; pass < 2; ++pass) {
    const float4 v = *(const float4*)&sU[o4 << 2];

    float d[16];
    #pragma unroll
    for (int j = 0; j < 16; ++j) {
      d[j] = preg[j].x * v.x + preg[j].y * v.y + preg[j].z * v.z + preg[j].w * v.w;
    }
    #pragma unroll
    for (int j = 0; j < 16; ++j) {
      d[j] += __shfl_xor(d[j], 1);
      d[j] += __shfl_xor(d[j], 2);
      d[j] += __shfl_xor(d[j], 4);
    }

    float mx = d[0];
    #pragma unroll
    for (int j = 1; j < 16; ++j) mx = fmaxf(mx, d[j]);
    mx = fmaxf(mx, __shfl_xor(mx, 8));
    mx = fmaxf(mx, __shfl_xor(mx, 16));
    mx = fmaxf(mx, __shfl_xor(mx, 32));
    if (lane == 0) sM[wid] = mx;
    __syncthreads();
    float M = sM[0];
    #pragma unroll
    for (int w2 = 1; w2 < 16; ++w2) M = fmaxf(M, sM[w2]);

    float z = 0.f;
    float4 acc = make_float4(0.f, 0.f, 0.f, 0.f);
    #pragma unroll
    for (int j = 0; j < 16; ++j) { d[j] = __expf(d[j] - M); z += d[j]; }
    #pragma unroll
    for (int j = 0; j < 16; ++j) {
      acc.x = fmaf(d[j], preg[j].x, acc.x);
      acc.y = fmaf(d[j], preg[j].y, acc.y);
      acc.z = fmaf(d[j], preg[j].z, acc.z);
      acc.w = fmaf(d[j], preg[j].w, acc.w);
    }
    #pragma unroll
    for (int m = 8; m <= 32; m <<= 1) {
      z     += __shfl_xor(z, m);
      acc.x += __shfl_xor(acc.x, m);
      acc.y += __shfl_xor(acc.y, m);
      acc.z += __shfl_xor(acc.z, m);
      acc.w += __shfl_xor(acc.w, m);
    }
    if (lane < 8) {
      *(float4*)&swv[(wid << 5) + (o4 << 2)] = acc;
      if (o4 == 0) sZ[wid] = z;
    }
    __syncthreads();
    if (t < OO) {
      float zz = 0.f, s = 0.f;
      #pragma unroll
      for (int w2 = 0; w2 < 16; ++w2) { zz += sZ[w2]; s += swv[(w2 << 5) + t]; }
      const float fo = s / zz;
      if (pass == 0) {
        sU[t] += sigmoidf_(fo);
      } else {
        out[((size_t)((k0 + kl) * BB + b)) * OO + t] = sigmoidf_(fo);
      }
    }
    __syncthreads();
  }
}

// ---------------- Fallback: round-1 fused kernel (verified, 226 us) --------
#define THREADS 1024
#define PLDS_FLOATS (1024 * 32)
#define SWV_OFF PLDS_FLOATS
#define SU_OFF (SWV_OFF + 16 * 32)
#define SM_OFF (SU_OFF + 32)
#define SZ_OFF (SM_OFF + 16)
#define SMEM_FLOATS (SZ_OFF + 16)
#define SMEM_BYTES (SMEM_FLOATS * 4)

__global__ void __launch_bounds__(THREADS, 4)
capsule_fused(const float* __restrict__ x, const float* __restrict__ w,
              float* __restrict__ out) {
  extern __shared__ float smem[];
  float* Plds = smem;
  float* swv  = smem + SWV_OFF;
  float* sU   = smem + SU_OFF;
  float* sM   = smem + SM_OFF;
  float* sZ   = smem + SZ_OFF;

  const int t    = threadIdx.x;
  const int o4   = t & 7;
  const int G    = t >> 3;
  const int lane = t & 63;
  const int wid  = t >> 6;
  const int swz  = ((o4 ^ (G & 7)) << 2);

  const int bid  = blockIdx.x;
  const int xcd  = bid & 7;
  const int slot = bid >> 3;
  const int k    = xcd + 8 * (slot >> 5);
  const int b    = slot & 31;

  const float* __restrict__ xb = x + (size_t)b * (RR * CC);
  const float* __restrict__ wk = w + (size_t)k * ((size_t)RR * CC * OO);

  float4 preg[8];
  float4 cs = make_float4(0.f, 0.f, 0.f, 0.f);

  #pragma unroll
  for (int j = 0; j < 16; ++j) {
    const int r = ((j & 8) ? 1024 : 0) + 8 * G + (j & 7);
    const float* xr = xb + r * CC;
    float xs[16];
    *(float4*)&xs[0]  = *(const float4*)(xr + 0);
    *(float4*)&xs[4]  = *(const float4*)(xr + 4);
    *(float4*)&xs[8]  = *(const float4*)(xr + 8);
    *(float4*)&xs[12] = *(const float4*)(xr + 12);
    const float* wr = wk + (size_t)r * (CC * OO) + (o4 << 2);
    float4 a = make_float4(0.f, 0.f, 0.f, 0.f);
    #pragma unroll
    for (int c = 0; c < CC; ++c) {
      const float4 wv = *(const float4*)(wr + c * OO);
      a.x = fmaf(xs[c], wv.x, a.x);
      a.y = fmaf(xs[c], wv.y, a.y);
      a.z = fmaf(xs[c], wv.z, a.z);
      a.w = fmaf(xs[c], wv.w, a.w);
    }
    if (j < 8) {
      *(float4*)&Plds[((8 * G + (j & 7)) << 5) + swz] = a;
    } else {
      preg[j - 8] = a;
    }
    cs.x += a.x; cs.y += a.y; cs.z += a.z; cs.w += a.w;
  }

  #pragma unroll
  for (int m = 8; m <= 32; m <<= 1) {
    cs.x += __shfl_xor(cs.x, m);
    cs.y += __shfl_xor(cs.y, m);
    cs.z += __shfl_xor(cs.z, m);
    cs.w += __shfl_xor(cs.w, m);
  }
  if (lane < 8) *(float4*)&swv[(wid << 5) + (o4 << 2)] = cs;
  __syncthreads();
  if (t < OO) {
    float s = 0.f;
    #pragma unroll
    for (int w2 = 0; w2 < 16; ++w2) s += swv[(w2 << 5) + t];
    sU[t] = sigmoidf_(s * (1.0f / 2048.0f));
  }
  __syncthreads();

  #pragma unroll 1
  for (int pass = 0; pass < 2; ++pass) {
    const float4 v = *(const float4*)&sU[o4 << 2];
    float d[16];
    #pragma unroll
    for (int j = 0; j < 8; ++j) {
      const float4 p = *(const float4*)&Plds[((8 * G + j) << 5) + swz];
      d[j] = p.x * v.x + p.y * v.y + p.z * v.z + p.w * v.w;
    }
    #pragma unroll
    for (int j = 0; j < 8; ++j) {
      const float4 p = preg[j];
      d[8 + j] = p.x * v.x + p.y * v.y + p.z * v.z + p.w * v.w;
    }
    #pragma unroll
    for (int j = 0; j < 16; ++j) {
      d[j] += __shfl_xor(d[j], 1);
      d[j] += __shfl_xor(d[j], 2);
      d[j] += __shfl_xor(d[j], 4);
    }
    float mx = d[0];
    #pragma unroll
    for (int j = 1; j < 16; ++j) mx = fmaxf(mx, d[j]);
    mx = fmaxf(mx, __shfl_xor(mx, 8));
    mx = fmaxf(mx, __shfl_xor(mx, 16));
    mx = fmaxf(mx, __shfl_xor(mx, 32));
    if (lane == 0) sM[wid] = mx;
    __syncthreads();
    float M = sM[0];
    #pragma unroll
    for (int w2 = 1; w2 < 16; ++w2) M = fmaxf(M, sM[w2]);

    float z = 0.f;
    float4 acc = make_float4(0.f, 0.f, 0.f, 0.f);
    #pragma unroll
    for (int j = 0; j < 16; ++j) { d[j] = __expf(d[j] - M); z += d[j]; }
    #pragma unroll
    for (int j = 0; j < 8; ++j) {
      const float4 p = *(const float4*)&Plds[((8 * G + j) << 5) + swz];
      acc.x = fmaf(d[j], p.x, acc.x);
      acc.y = fmaf(d[j], p.y, acc.y);
      acc.z = fmaf(d[j], p.z, acc.z);
      acc.w = fmaf(d[j], p.w, acc.w);
    }
    #pragma unroll
    for (int j = 0; j < 8; ++j) {
      const float4 p = preg[j];
      acc.x = fmaf(d[8 + j], p.x, acc.x);
      acc.y = fmaf(d[8 + j], p.y, acc.y);
      acc.z = fmaf(d[8 + j], p.z, acc.z);
      acc.w = fmaf(d[8 + j], p.w, acc.w);
    }
    #pragma unroll
    for (int m = 8; m <= 32; m <<= 1) {
      z     += __shfl_xor(z, m);
      acc.x += __shfl_xor(acc.x, m);
      acc.y += __shfl_xor(acc.y, m);
      acc.z += __shfl_xor(acc.z, m);
      acc.w += __shfl_xor(acc.w, m);
    }
    if (lane < 8) {
      *(float4*)&swv[(wid << 5) + (o4 << 2)] = acc;
      if (o4 == 0) sZ[wid] = z;
    }
    __syncthreads();
    if (t < OO) {
      float zz = 0.f, s = 0.f;
      #pragma unroll
      for (int w2 = 0; w2 < 16; ++w2) { zz += sZ[w2]; s += swv[(w2 << 5) + t]; }
      const float fo = s / zz;
      if (pass == 0) {
        sU[t] = sU[t] + sigmoidf_(fo);
      } else {
        out[((k << 5) + b) * OO + t] = sigmoidf_(fo);
      }
    }
    __syncthreads();
  }
}

extern "C" void kernel_launch(void* const* d_in, const int* in_sizes, int n_in,
                              void* d_out, int out_size, void* d_ws, size_t ws_size,
                              hipStream_t stream) {
  const float* x = (const float*)d_in[0];
  const float* w = (const float*)d_in[1];
  float* out = (float*)d_out;
  (void)in_sizes; (void)n_in; (void)out_size;

  const size_t perK = (size_t)BB * RR * OO * sizeof(float);  // 8 MB per k
  const size_t xTsz = (size_t)BB * RR * CC * sizeof(float);  // 4 MB
  int KCHUNK = 0;
  if      (ws_size >= 8 * perK + xTsz) KCHUNK = 8;   // 68 MB working set << MALL
  else if (ws_size >= 4 * perK + xTsz) KCHUNK = 4;

  if (KCHUNK == 0) {
    hipFuncSetAttribute(reinterpret_cast<const void*>(capsule_fused),
                        hipFuncAttributeMaxDynamicSharedMemorySize, SMEM_BYTES);
    capsule_fused<<<dim3(KK * BB), dim3(THREADS), SMEM_BYTES, stream>>>(x, w, out);
    return;
  }

  float* P  = (float*)d_ws;
  float* xT = (float*)((char*)d_ws + KCHUNK * perK);

  transpose_x<<<dim3(RR), dim3(256), 0, stream>>>(x, xT);
  for (int k0 = 0; k0 < KK; k0 += KCHUNK) {
    capsule_priors3<<<dim3(KCHUNK * 128), dim3(256), 0, stream>>>(xT, w, P, k0);
    capsule_route<<<dim3(KCHUNK * 32), dim3(1024), 0, stream>>>(P, out, k0);
  }
}

// Round 14
// 178.637 us; speedup vs baseline: 1.1679x; 1.1679x over previous
//
#include <hip/hip_runtime.h>

// CapsuleLayer dynamic routing — two-phase, fp32-exact. FINAL (R10 revert).
//   P[k,b,r,o] = sum_c x[b,r,c] * w[k,r,c,o]   (K=B=32, R=2048, C=16, O=32)
//   u0 = sigmoid(colsum(P)/R); f(v) = P^T softmax(P v)
//   u1 = sigmoid(f(u0)); out = sigmoid(f(u0+u1))
//
// Session ledger (verified results):
//   R1 fused 226us -> R6/R10 two-phase 178.8us (best) ; levers exhausted:
//   burst depth null (R10), occupancy negative (R11), nt-load negative (R13),
//   LDS staging negative (R7/R8), min-waves launch_bounds = scratch-spill
//   trap (R5/R9: VGPR forced to 48/64, 4x HBM amplification via scratch).
//   Priors streams ~100 MB/chunk at ~3 TB/s (w read once; P MALL-resident at
//   KCHUNK=8); route reads P at ~7 TB/s from L3. Empirical floor ~179 us.

#define KK 32
#define BB 32
#define RR 2048
#define CC 16
#define OO 32

__device__ __forceinline__ float sigmoidf_(float v) {
  return 1.0f / (1.0f + __expf(-v));
}

// ---------------- Phase 0: x[B][R][C] -> xT[R][C][B] (once) ----------------
__global__ void __launch_bounds__(256)
transpose_x(const float* __restrict__ x, float* __restrict__ xT) {
  const int r = blockIdx.x;          // 0..2047
  const int t = threadIdx.x;
  const int b = t >> 3;              // 0..31
  const int c = (t & 7) * 2;         // 0,2,..,14
  const float2 v = *(const float2*)(x + ((size_t)b * RR + r) * CC + c);
  xT[((size_t)r * CC + c) * BB + b]     = v.x;
  xT[((size_t)r * CC + c + 1) * BB + b] = v.y;
}

// ---------------- Phase 1: priors einsum (R6 geometry, 2-c bursts) ---------
// grid = KCHUNK*128 x 256 thr. Block = (kl = bid>>7, 16-row tile rt).
// Lane: og = l&3, bg = (l>>2)&3, rq = l>>4; wave wid owns rows wid*4+rq.
// Thread tile 8b x 8o (acc 64 VGPR). Loads in 2-c pairs (8 in flight).
// NO min-waves launch_bounds arg (spill trap, see header).
__global__ void __launch_bounds__(256)
capsule_priors3(const float* __restrict__ xT, const float* __restrict__ w,
                float* __restrict__ P, int k0) {
  const int bid  = blockIdx.x;
  const int kl   = bid >> 7;
  const int rt   = bid & 127;
  const int t    = threadIdx.x;
  const int lane = t & 63;
  const int wid  = t >> 6;           // 0..3
  const int og   = lane & 3;
  const int bg   = (lane >> 2) & 3;
  const int rq   = lane >> 4;        // 0..3
  const int r    = rt * 16 + wid * 4 + rq;
  const int k    = k0 + kl;

  const float* __restrict__ xr = xT + ((size_t)r * CC) * BB + bg * 8;
  const float* __restrict__ wr = w + (size_t)k * ((size_t)RR * CC * OO)
                                   + ((size_t)r * CC) * OO + og * 8;

  float4 acc[8][2];
  #pragma unroll
  for (int bb = 0; bb < 8; ++bb) {
    acc[bb][0] = make_float4(0.f, 0.f, 0.f, 0.f);
    acc[bb][1] = make_float4(0.f, 0.f, 0.f, 0.f);
  }

  #pragma unroll
  for (int q = 0; q < 8; ++q) {
    // pair burst: 8 independent loads for c = 2q, 2q+1
    float4 xfA0, xfA1, wfA0, wfA1, xfB0, xfB1, wfB0, wfB1;
    {
      const int cA = 2 * q, cB = 2 * q + 1;
      xfA0 = *(const float4*)(xr + cA * BB);
      xfA1 = *(const float4*)(xr + cA * BB + 4);
      wfA0 = *(const float4*)(wr + cA * OO);
      wfA1 = *(const float4*)(wr + cA * OO + 4);
      xfB0 = *(const float4*)(xr + cB * BB);
      xfB1 = *(const float4*)(xr + cB * BB + 4);
      wfB0 = *(const float4*)(wr + cB * OO);
      wfB1 = *(const float4*)(wr + cB * OO + 4);
    }
    {
      const float xs[8] = {xfA0.x, xfA0.y, xfA0.z, xfA0.w,
                           xfA1.x, xfA1.y, xfA1.z, xfA1.w};
      #pragma unroll
      for (int bb = 0; bb < 8; ++bb) {
        const float s = xs[bb];
        acc[bb][0].x = fmaf(s, wfA0.x, acc[bb][0].x);
        acc[bb][0].y = fmaf(s, wfA0.y, acc[bb][0].y);
        acc[bb][0].z = fmaf(s, wfA0.z, acc[bb][0].z);
        acc[bb][0].w = fmaf(s, wfA0.w, acc[bb][0].w);
        acc[bb][1].x = fmaf(s, wfA1.x, acc[bb][1].x);
        acc[bb][1].y = fmaf(s, wfA1.y, acc[bb][1].y);
        acc[bb][1].z = fmaf(s, wfA1.z, acc[bb][1].z);
        acc[bb][1].w = fmaf(s, wfA1.w, acc[bb][1].w);
      }
    }
    {
      const float xs[8] = {xfB0.x, xfB0.y, xfB0.z, xfB0.w,
                           xfB1.x, xfB1.y, xfB1.z, xfB1.w};
      #pragma unroll
      for (int bb = 0; bb < 8; ++bb) {
        const float s = xs[bb];
        acc[bb][0].x = fmaf(s, wfB0.x, acc[bb][0].x);
        acc[bb][0].y = fmaf(s, wfB0.y, acc[bb][0].y);
        acc[bb][0].z = fmaf(s, wfB0.z, acc[bb][0].z);
        acc[bb][0].w = fmaf(s, wfB0.w, acc[bb][0].w);
        acc[bb][1].x = fmaf(s, wfB1.x, acc[bb][1].x);
        acc[bb][1].y = fmaf(s, wfB1.y, acc[bb][1].y);
        acc[bb][1].z = fmaf(s, wfB1.z, acc[bb][1].z);
        acc[bb][1].w = fmaf(s, wfB1.w, acc[bb][1].w);
      }
    }
  }

  #pragma unroll
  for (int bb = 0; bb < 8; ++bb) {
    const int b = bg * 8 + bb;
    float* Pd = P + (((size_t)kl * BB + b) * RR + r) * OO + og * 8;
    *(float4*)(Pd)     = acc[bb][0];
    *(float4*)(Pd + 4) = acc[bb][1];
  }
}

// ---------------- Phase 2: routing (unchanged from R3/R4/R6, verified) ----
__global__ void __launch_bounds__(1024, 4)
capsule_route(const float* __restrict__ P, float* __restrict__ out, int k0) {
  __shared__ float swv[512];
  __shared__ float sU[32];
  __shared__ float sM[16];
  __shared__ float sZ[16];

  const int bid  = blockIdx.x;
  const int kl   = bid >> 5;
  const int b    = bid & 31;
  const int t    = threadIdx.x;
  const int o4   = t & 7;
  const int G    = t >> 3;
  const int lane = t & 63;
  const int wid  = t >> 6;

  const float* __restrict__ Pb = P + ((size_t)kl * BB + b) * ((size_t)RR * OO);

  float4 preg[16];
  float4 cs = make_float4(0.f, 0.f, 0.f, 0.f);
  #pragma unroll
  for (int j = 0; j < 16; ++j) {
    preg[j] = *(const float4*)(Pb + (size_t)(j * 128 + G) * OO + (o4 << 2));
    cs.x += preg[j].x; cs.y += preg[j].y; cs.z += preg[j].z; cs.w += preg[j].w;
  }

  #pragma unroll
  for (int m = 8; m <= 32; m <<= 1) {
    cs.x += __shfl_xor(cs.x, m);
    cs.y += __shfl_xor(cs.y, m);
    cs.z += __shfl_xor(cs.z, m);
    cs.w += __shfl_xor(cs.w, m);
  }
  if (lane < 8) *(float4*)&swv[(wid << 5) + (o4 << 2)] = cs;
  __syncthreads();
  if (t < OO) {
    float s = 0.f;
    #pragma unroll
    for (int w2 = 0; w2 < 16; ++w2) s += swv[(w2 << 5) + t];
    sU[t] = sigmoidf_(s * (1.0f / 2048.0f));
  }
  __syncthreads();

  #pragma unroll 1
  for (int pass = 0; pass < 2; ++pass) {
    const float4 v = *(const float4*)&sU[o4 << 2];

    float d[16];
    #pragma unroll
    for (int j = 0; j < 16; ++j) {
      d[j] = preg[j].x * v.x + preg[j].y * v.y + preg[j].z * v.z + preg[j].w * v.w;
    }
    #pragma unroll
    for (int j = 0; j < 16; ++j) {
      d[j] += __shfl_xor(d[j], 1);
      d[j] += __shfl_xor(d[j], 2);
      d[j] += __shfl_xor(d[j], 4);
    }

    float mx = d[0];
    #pragma unroll
    for (int j = 1; j < 16; ++j) mx = fmaxf(mx, d[j]);
    mx = fmaxf(mx, __shfl_xor(mx, 8));
    mx = fmaxf(mx, __shfl_xor(mx, 16));
    mx = fmaxf(mx, __shfl_xor(mx, 32));
    if (lane == 0) sM[wid] = mx;
    __syncthreads();
    float M = sM[0];
    #pragma unroll
    for (int w2 = 1; w2 < 16; ++w2) M = fmaxf(M, sM[w2]);

    float z = 0.f;
    float4 acc = make_float4(0.f, 0.f, 0.f, 0.f);
    #pragma unroll
    for (int j = 0; j < 16; ++j) { d[j] = __expf(d[j] - M); z += d[j]; }
    #pragma unroll
    for (int j = 0; j < 16; ++j) {
      acc.x = fmaf(d[j], preg[j].x, acc.x);
      acc.y = fmaf(d[j], preg[j].y, acc.y);
      acc.z = fmaf(d[j], preg[j].z, acc.z);
      acc.w = fmaf(d[j], preg[j].w, acc.w);
    }
    #pragma unroll
    for (int m = 8; m <= 32; m <<= 1) {
      z     += __shfl_xor(z, m);
      acc.x += __shfl_xor(acc.x, m);
      acc.y += __shfl_xor(acc.y, m);
      acc.z += __shfl_xor(acc.z, m);
      acc.w += __shfl_xor(acc.w, m);
    }
    if (lane < 8) {
      *(float4*)&swv[(wid << 5) + (o4 << 2)] = acc;
      if (o4 == 0) sZ[wid] = z;
    }
    __syncthreads();
    if (t < OO) {
      float zz = 0.f, s = 0.f;
      #pragma unroll
      for (int w2 = 0; w2 < 16; ++w2) { zz += sZ[w2]; s += swv[(w2 << 5) + t]; }
      const float fo = s / zz;
      if (pass == 0) {
        sU[t] += sigmoidf_(fo);
      } else {
        out[((size_t)((k0 + kl) * BB + b)) * OO + t] = sigmoidf_(fo);
      }
    }
    __syncthreads();
  }
}

// ---------------- Fallback: round-1 fused kernel (verified, 226 us) --------
#define THREADS 1024
#define PLDS_FLOATS (1024 * 32)
#define SWV_OFF PLDS_FLOATS
#define SU_OFF (SWV_OFF + 16 * 32)
#define SM_OFF (SU_OFF + 32)
#define SZ_OFF (SM_OFF + 16)
#define SMEM_FLOATS (SZ_OFF + 16)
#define SMEM_BYTES (SMEM_FLOATS * 4)

__global__ void __launch_bounds__(THREADS, 4)
capsule_fused(const float* __restrict__ x, const float* __restrict__ w,
              float* __restrict__ out) {
  extern __shared__ float smem[];
  float* Plds = smem;
  float* swv  = smem + SWV_OFF;
  float* sU   = smem + SU_OFF;
  float* sM   = smem + SM_OFF;
  float* sZ   = smem + SZ_OFF;

  const int t    = threadIdx.x;
  const int o4   = t & 7;
  const int G    = t >> 3;
  const int lane = t & 63;
  const int wid  = t >> 6;
  const int swz  = ((o4 ^ (G & 7)) << 2);

  const int bid  = blockIdx.x;
  const int xcd  = bid & 7;
  const int slot = bid >> 3;
  const int k    = xcd + 8 * (slot >> 5);
  const int b    = slot & 31;

  const float* __restrict__ xb = x + (size_t)b * (RR * CC);
  const float* __restrict__ wk = w + (size_t)k * ((size_t)RR * CC * OO);

  float4 preg[8];
  float4 cs = make_float4(0.f, 0.f, 0.f, 0.f);

  #pragma unroll
  for (int j = 0; j < 16; ++j) {
    const int r = ((j & 8) ? 1024 : 0) + 8 * G + (j & 7);
    const float* xr = xb + r * CC;
    float xs[16];
    *(float4*)&xs[0]  = *(const float4*)(xr + 0);
    *(float4*)&xs[4]  = *(const float4*)(xr + 4);
    *(float4*)&xs[8]  = *(const float4*)(xr + 8);
    *(float4*)&xs[12] = *(const float4*)(xr + 12);
    const float* wr = wk + (size_t)r * (CC * OO) + (o4 << 2);
    float4 a = make_float4(0.f, 0.f, 0.f, 0.f);
    #pragma unroll
    for (int c = 0; c < CC; ++c) {
      const float4 wv = *(const float4*)(wr + c * OO);
      a.x = fmaf(xs[c], wv.x, a.x);
      a.y = fmaf(xs[c], wv.y, a.y);
      a.z = fmaf(xs[c], wv.z, a.z);
      a.w = fmaf(xs[c], wv.w, a.w);
    }
    if (j < 8) {
      *(float4*)&Plds[((8 * G + (j & 7)) << 5) + swz] = a;
    } else {
      preg[j - 8] = a;
    }
    cs.x += a.x; cs.y += a.y; cs.z += a.z; cs.w += a.w;
  }

  #pragma unroll
  for (int m = 8; m <= 32; m <<= 1) {
    cs.x += __shfl_xor(cs.x, m);
    cs.y += __shfl_xor(cs.y, m);
    cs.z += __shfl_xor(cs.z, m);
    cs.w += __shfl_xor(cs.w, m);
  }
  if (lane < 8) *(float4*)&swv[(wid << 5) + (o4 << 2)] = cs;
  __syncthreads();
  if (t < OO) {
    float s = 0.f;
    #pragma unroll
    for (int w2 = 0; w2 < 16; ++w2) s += swv[(w2 << 5) + t];
    sU[t] = sigmoidf_(s * (1.0f / 2048.0f));
  }
  __syncthreads();

  #pragma unroll 1
  for (int pass = 0; pass < 2; ++pass) {
    const float4 v = *(const float4*)&sU[o4 << 2];
    float d[16];
    #pragma unroll
    for (int j = 0; j < 8; ++j) {
      const float4 p = *(const float4*)&Plds[((8 * G + j) << 5) + swz];
      d[j] = p.x * v.x + p.y * v.y + p.z * v.z + p.w * v.w;
    }
    #pragma unroll
    for (int j = 0; j < 8; ++j) {
      const float4 p = preg[j];
      d[8 + j] = p.x * v.x + p.y * v.y + p.z * v.z + p.w * v.w;
    }
    #pragma unroll
    for (int j = 0; j < 16; ++j) {
      d[j] += __shfl_xor(d[j], 1);
      d[j] += __shfl_xor(d[j], 2);
      d[j] += __shfl_xor(d[j], 4);
    }
    float mx = d[0];
    #pragma unroll
    for (int j = 1; j < 16; ++j) mx = fmaxf(mx, d[j]);
    mx = fmaxf(mx, __shfl_xor(mx, 8));
    mx = fmaxf(mx, __shfl_xor(mx, 16));
    mx = fmaxf(mx, __shfl_xor(mx, 32));
    if (lane == 0) sM[wid] = mx;
    __syncthreads();
    float M = sM[0];
    #pragma unroll
    for (int w2 = 1; w2 < 16; ++w2) M = fmaxf(M, sM[w2]);

    float z = 0.f;
    float4 acc = make_float4(0.f, 0.f, 0.f, 0.f);
    #pragma unroll
    for (int j = 0; j < 16; ++j) { d[j] = __expf(d[j] - M); z += d[j]; }
    #pragma unroll
    for (int j = 0; j < 8; ++j) {
      const float4 p = *(const float4*)&Plds[((8 * G + j) << 5) + swz];
      acc.x = fmaf(d[j], p.x, acc.x);
      acc.y = fmaf(d[j], p.y, acc.y);
      acc.z = fmaf(d[j], p.z, acc.z);
      acc.w = fmaf(d[j], p.w, acc.w);
    }
    #pragma unroll
    for (int j = 0; j < 8; ++j) {
      const float4 p = preg[j];
      acc.x = fmaf(d[8 + j], p.x, acc.x);
      acc.y = fmaf(d[8 + j], p.y, acc.y);
      acc.z = fmaf(d[8 + j], p.z, acc.z);
      acc.w = fmaf(d[8 + j], p.w, acc.w);
    }
    #pragma unroll
    for (int m = 8; m <= 32; m <<= 1) {
      z     += __shfl_xor(z, m);
      acc.x += __shfl_xor(acc.x, m);
      acc.y += __shfl_xor(acc.y, m);
      acc.z += __shfl_xor(acc.z, m);
      acc.w += __shfl_xor(acc.w, m);
    }
    if (lane < 8) {
      *(float4*)&swv[(wid << 5) + (o4 << 2)] = acc;
      if (o4 == 0) sZ[wid] = z;
    }
    __syncthreads();
    if (t < OO) {
      float zz = 0.f, s = 0.f;
      #pragma unroll
      for (int w2 = 0; w2 < 16; ++w2) { zz += sZ[w2]; s += swv[(w2 << 5) + t]; }
      const float fo = s / zz;
      if (pass == 0) {
        sU[t] = sU[t] + sigmoidf_(fo);
      } else {
        out[((k << 5) + b) * OO + t] = sigmoidf_(fo);
      }
    }
    __syncthreads();
  }
}

extern "C" void kernel_launch(void* const* d_in, const int* in_sizes, int n_in,
                              void* d_out, int out_size, void* d_ws, size_t ws_size,
                              hipStream_t stream) {
  const float* x = (const float*)d_in[0];
  const float* w = (const float*)d_in[1];
  float* out = (float*)d_out;
  (void)in_sizes; (void)n_in; (void)out_size;

  const size_t perK = (size_t)BB * RR * OO * sizeof(float);  // 8 MB per k
  const size_t xTsz = (size_t)BB * RR * CC * sizeof(float);  // 4 MB
  int KCHUNK = 0;
  if      (ws_size >= 8 * perK + xTsz) KCHUNK = 8;   // 68 MB working set << MALL
  else if (ws_size >= 4 * perK + xTsz) KCHUNK = 4;

  if (KCHUNK == 0) {
    hipFuncSetAttribute(reinterpret_cast<const void*>(capsule_fused),
                        hipFuncAttributeMaxDynamicSharedMemorySize, SMEM_BYTES);
    capsule_fused<<<dim3(KK * BB), dim3(THREADS), SMEM_BYTES, stream>>>(x, w, out);
    return;
  }

  float* P  = (float*)d_ws;
  float* xT = (float*)((char*)d_ws + KCHUNK * perK);

  transpose_x<<<dim3(RR), dim3(256), 0, stream>>>(x, xT);
  for (int k0 = 0; k0 < KK; k0 += KCHUNK) {
    capsule_priors3<<<dim3(KCHUNK * 128), dim3(256), 0, stream>>>(xT, w, P, k0);
    capsule_route<<<dim3(KCHUNK * 32), dim3(1024), 0, stream>>>(P, out, k0);
  }
}